// Round 6
// baseline (248.608 us; speedup 1.0000x reference)
//
#include <hip/hip_runtime.h>
#include <math.h>

// Cross-bilateral filter, B=4, C=3, H=720, W=1280, WIN=11 (pad=5), f32.
//
// R6: array-free streaming inner loop (R5 kept big per-row arrays that the
// compiler could not hold in 68 VGPRs -> re-read/re-cvt per pixel).
//  - Difference-form weights (accuracy-proven): guides pre-scaled by
//    sqrt(log2e/sigma), 8 x f16 per uint4 LDS cell; d = g - c (v_pk_add neg),
//    e = sum d^2 (4x v_dot2_f32_f16), w = exp2(-e).
//  - Input {i0,i1,i2,1.0} as 4 x f16 (uint2). Accumulate with
//    fmaf(w,(float)h,acc) -> v_fma_mix_f32 (no unpack cvts, f32 accuracy).
//  - 4 vertically adjacent pixels/thread (32x32 tile); rows processed by
//    do_row<KLO,KHI>: ramp 0..2, steady 3..10 (all 4 px), ramp 11..13.
//    All acc/center indices compile-time; ~50 live VGPRs.
//  - LDS 42x42x24 = 42.3 KB -> 3 blocks/CU.

#define HH   720
#define WW   1280
#define PAD  5
#define WIN  11
#define TW   32
#define TH   32
#define HW2  42            // halo dim = TW + 2*PAD

typedef _Float16 h2 __attribute__((ext_vector_type(2)));

__device__ __forceinline__ unsigned pk2(float a, float b) {
    unsigned lo = __builtin_bit_cast(unsigned short, (_Float16)a);
    unsigned hi = __builtin_bit_cast(unsigned short, (_Float16)b);
    return lo | (hi << 16);
}

__device__ __forceinline__ float fdot2(h2 a, h2 b, float c) {
#if __has_builtin(__builtin_amdgcn_fdot2)
    return __builtin_amdgcn_fdot2(a, b, c, false);
#else
    return fmaf((float)a.x, (float)b.x, fmaf((float)a.y, (float)b.y, c));
#endif
}

__device__ __forceinline__ h2 bch2(unsigned u) { return __builtin_bit_cast(h2, u); }

struct Ctr { h2 c0, c1, c2, c3; };

__device__ __forceinline__ void tap_one(const Ctr& c, uint4 g, h2 i01, h2 i2s,
                                        float4& a) {
    h2 d0 = bch2(g.x) - c.c0;
    h2 d1 = bch2(g.y) - c.c1;
    h2 d2 = bch2(g.z) - c.c2;
    h2 d3 = bch2(g.w) - c.c3;
    float e = fdot2(d0, d0, fdot2(d1, d1, fdot2(d2, d2, fdot2(d3, d3, 0.f))));
    float w = __builtin_amdgcn_exp2f(-e);
    a.x = fmaf(w, (float)i01.x, a.x);   // v_fma_mix_f32
    a.y = fmaf(w, (float)i01.y, a.y);
    a.z = fmaf(w, (float)i2s.x, a.z);
    a.w += w;
}

template<int KLO, int KHI>
__device__ __forceinline__ void do_row(const uint4* __restrict__ rg,
                                       const uint2* __restrict__ ri,
                                       const Ctr* c, float4* acc) {
#pragma unroll
    for (int dx = 0; dx < WIN; ++dx) {
        uint4 g  = rg[dx];
        uint2 t  = ri[dx];
        h2 i01 = bch2(t.x), i2s = bch2(t.y);
#pragma unroll
        for (int k = KLO; k <= KHI; ++k)
            tap_one(c[k], g, i01, i2s, acc[k]);
    }
}

__global__ __launch_bounds__(256, 3)
void xbilateral_kernel(const float* __restrict__ inp,
                       const float* __restrict__ alb,
                       const float* __restrict__ nrm,
                       const float* __restrict__ dep,
                       float* __restrict__ out)
{
    __shared__ uint4 sG[HW2][HW2];   // 8 x f16: {a0,a1,a2,dep, n0,n1,n2, 0} scaled
    __shared__ uint2 sI[HW2][HW2];   // 4 x f16: {i0,i1,i2,1.0}

    const int tid = threadIdx.x;
    const int lx  = tid & 31;        // 0..31
    const int ly  = tid >> 5;        // 0..7
    const int bx0 = blockIdx.x * TW;
    const int by0 = blockIdx.y * TH;
    const int b   = blockIdx.z;

    const float kA = 12.01122406f;   // sqrt(1.44269504/0.01)
    const float kN = 3.79828255f;    // sqrt(1.44269504/0.1)  (also depth)

    const size_t plane = (size_t)HH * WW;
    const float* albB = alb + (size_t)b * 3 * plane;
    const float* nrmB = nrm + (size_t)b * 3 * plane;
    const float* inpB = inp + (size_t)b * 3 * plane;
    const float* depB = dep + (size_t)b * plane;

    // ---- stage halo tile (clamped coords, scaled f16) ----
    for (int idx = tid; idx < HW2 * HW2; idx += 256) {
        int r = idx / HW2;
        int c = idx - r * HW2;
        int gy = by0 + r - PAD; gy = min(max(gy, 0), HH - 1);
        int gx = bx0 + c - PAD; gx = min(max(gx, 0), WW - 1);
        size_t o = (size_t)gy * WW + gx;
        float a0 = albB[o] * kA, a1 = albB[plane + o] * kA, a2 = albB[2 * plane + o] * kA;
        float n0 = nrmB[o] * kN, n1 = nrmB[plane + o] * kN, n2 = nrmB[2 * plane + o] * kN;
        float d0 = depB[o] * kN;
        sG[r][c] = make_uint4(pk2(a0, a1), pk2(a2, d0), pk2(n0, n1), pk2(n2, 0.f));
        float i0 = inpB[o], i1 = inpB[plane + o], i2 = inpB[2 * plane + o];
        sI[r][c] = make_uint2(pk2(i0, i1), pk2(i2, 1.f));
    }
    __syncthreads();

    // ---- per-thread: 4 vertically adjacent pixels, tile rows 4*ly + 0..3 ----
    const int py0 = 4 * ly;

    Ctr c[4];
#pragma unroll
    for (int k = 0; k < 4; ++k) {
        uint4 g = sG[py0 + k + PAD][lx + PAD];
        c[k].c0 = bch2(g.x);
        c[k].c1 = bch2(g.y);
        c[k].c2 = bch2(g.z);
        c[k].c3 = bch2(g.w);
    }

    float4 acc[4];
#pragma unroll
    for (int k = 0; k < 4; ++k) acc[k] = make_float4(0.f, 0.f, 0.f, 0.f);

    // ramp-up rows t = 0,1,2 (pixel k active iff t-10 <= k <= t)
    do_row<0, 0>(&sG[py0 + 0][lx], &sI[py0 + 0][lx], c, acc);
    do_row<0, 1>(&sG[py0 + 1][lx], &sI[py0 + 1][lx], c, acc);
    do_row<0, 2>(&sG[py0 + 2][lx], &sI[py0 + 2][lx], c, acc);
    // steady rows t = 3..10: all four pixels
#pragma unroll 1
    for (int t = 3; t <= 10; ++t)
        do_row<0, 3>(&sG[py0 + t][lx], &sI[py0 + t][lx], c, acc);
    // ramp-down rows t = 11,12,13
    do_row<1, 3>(&sG[py0 + 11][lx], &sI[py0 + 11][lx], c, acc);
    do_row<2, 3>(&sG[py0 + 12][lx], &sI[py0 + 12][lx], c, acc);
    do_row<3, 3>(&sG[py0 + 13][lx], &sI[py0 + 13][lx], c, acc);

    // ---- write out (guard H tail: grid y = ceil(720/32) = 23) ----
    const int ox = bx0 + lx;
    float* outB = out + (size_t)b * 3 * plane;
#pragma unroll
    for (int k = 0; k < 4; ++k) {
        int oy = by0 + py0 + k;
        if (oy < HH) {
            float inv = 1.0f / fmaxf(acc[k].w, 1e-10f);
            size_t o = (size_t)oy * WW + ox;
            outB[o]             = acc[k].x * inv;
            outB[plane + o]     = acc[k].y * inv;
            outB[2 * plane + o] = acc[k].z * inv;
        }
    }
}

extern "C" void kernel_launch(void* const* d_in, const int* in_sizes, int n_in,
                              void* d_out, int out_size, void* d_ws, size_t ws_size,
                              hipStream_t stream) {
    const float* inp = (const float*)d_in[0];
    const float* alb = (const float*)d_in[1];
    const float* nrm = (const float*)d_in[2];
    const float* dep = (const float*)d_in[3];
    // d_in[4] = win_size (always 11, compiled in)
    float* out = (float*)d_out;

    dim3 grid(WW / TW, (HH + TH - 1) / TH, 4);   // 40 x 23 x 4
    dim3 block(256);
    xbilateral_kernel<<<grid, block, 0, stream>>>(inp, alb, nrm, dep, out);
}

// Round 7
// 247.314 us; speedup vs baseline: 1.0052x; 1.0052x over previous
//
#include <hip/hip_runtime.h>
#include <math.h>

// Cross-bilateral filter, B=4, C=3, H=720, W=1280, WIN=11 (pad=5), f32.
//
// R7: R6 streaming structure, but SCRATCH-PROOF: no local arrays, no
// pointers-to-locals. Centers are 4 named Ctr structs, accumulators 4 named
// float4 passed by REFERENCE; pixel dispatch via if constexpr. R6's
// WRITE_SIZE=337MB (vs 43MB output) proved c[4]/acc[4] pointer-passing put
// them in scratch; R5's VGPR=68 proved its per-row arrays were
// rematerialized (re-read LDS per pixel). This version streams one cell
// (b128 + b64) and feeds all 4 pixels from registers.
//  - Difference-form weights (accuracy-proven): guides pre-scaled by
//    sqrt(log2e/sigma), 8 x f16 per uint4 cell; d = g - c (v_pk_add_f16 neg),
//    e = sum d^2 (4x v_dot2_f32_f16), w = exp2(-e).
//  - Input {i0,i1,i2,1.0} 4 x f16 (uint2); acc via fmaf(w,(float)h,acc)
//    -> v_fma_mix_f32.
//  - 4 vertically adjacent pixels/thread (32x32 tile), 14 window rows.
//  - LDS 42x42x24 = 42.3 KB -> 3 blocks/CU.

#define HH   720
#define WW   1280
#define PAD  5
#define WIN  11
#define TW   32
#define TH   32
#define HW2  42            // halo dim = TW + 2*PAD

typedef _Float16 h2 __attribute__((ext_vector_type(2)));

__device__ __forceinline__ unsigned pk2(float a, float b) {
    unsigned lo = __builtin_bit_cast(unsigned short, (_Float16)a);
    unsigned hi = __builtin_bit_cast(unsigned short, (_Float16)b);
    return lo | (hi << 16);
}

__device__ __forceinline__ float fdot2(h2 a, h2 b, float c) {
#if __has_builtin(__builtin_amdgcn_fdot2)
    return __builtin_amdgcn_fdot2(a, b, c, false);
#else
    return fmaf((float)a.x, (float)b.x, fmaf((float)a.y, (float)b.y, c));
#endif
}

__device__ __forceinline__ h2 bch2(unsigned u) { return __builtin_bit_cast(h2, u); }

struct Ctr { h2 c0, c1, c2, c3; };

__device__ __forceinline__ void tap_one(const Ctr& c, uint4 g, h2 i01, h2 i2s,
                                        float4& a) {
    h2 d0 = bch2(g.x) - c.c0;
    h2 d1 = bch2(g.y) - c.c1;
    h2 d2 = bch2(g.z) - c.c2;
    h2 d3 = bch2(g.w) - c.c3;
    float e = fdot2(d0, d0, fdot2(d1, d1, fdot2(d2, d2, fdot2(d3, d3, 0.f))));
    float w = __builtin_amdgcn_exp2f(-e);
    a.x = fmaf(w, (float)i01.x, a.x);   // v_fma_mix_f32
    a.y = fmaf(w, (float)i01.y, a.y);
    a.z = fmaf(w, (float)i2s.x, a.z);
    a.w += w;
}

template<int KLO, int KHI>
__device__ __forceinline__ void do_row(const uint4* __restrict__ rg,
                                       const uint2* __restrict__ ri,
                                       const Ctr& c0, const Ctr& c1,
                                       const Ctr& c2, const Ctr& c3,
                                       float4& a0, float4& a1,
                                       float4& a2, float4& a3) {
#pragma unroll
    for (int dx = 0; dx < WIN; ++dx) {
        uint4 g = rg[dx];
        uint2 t = ri[dx];
        h2 i01 = bch2(t.x), i2s = bch2(t.y);
        if constexpr (KLO <= 0 && 0 <= KHI) tap_one(c0, g, i01, i2s, a0);
        if constexpr (KLO <= 1 && 1 <= KHI) tap_one(c1, g, i01, i2s, a1);
        if constexpr (KLO <= 2 && 2 <= KHI) tap_one(c2, g, i01, i2s, a2);
        if constexpr (KLO <= 3 && 3 <= KHI) tap_one(c3, g, i01, i2s, a3);
    }
}

__global__ __launch_bounds__(256, 3)
void xbilateral_kernel(const float* __restrict__ inp,
                       const float* __restrict__ alb,
                       const float* __restrict__ nrm,
                       const float* __restrict__ dep,
                       float* __restrict__ out)
{
    __shared__ uint4 sG[HW2][HW2];   // 8 x f16: {a0,a1,a2,dep, n0,n1,n2, 0} scaled
    __shared__ uint2 sI[HW2][HW2];   // 4 x f16: {i0,i1,i2,1.0}

    const int tid = threadIdx.x;
    const int lx  = tid & 31;        // 0..31
    const int ly  = tid >> 5;        // 0..7
    const int bx0 = blockIdx.x * TW;
    const int by0 = blockIdx.y * TH;
    const int b   = blockIdx.z;

    const float kA = 12.01122406f;   // sqrt(1.44269504/0.01)
    const float kN = 3.79828255f;    // sqrt(1.44269504/0.1)  (also depth)

    const size_t plane = (size_t)HH * WW;
    const float* albB = alb + (size_t)b * 3 * plane;
    const float* nrmB = nrm + (size_t)b * 3 * plane;
    const float* inpB = inp + (size_t)b * 3 * plane;
    const float* depB = dep + (size_t)b * plane;

    // ---- stage halo tile (clamped coords, scaled f16) ----
    for (int idx = tid; idx < HW2 * HW2; idx += 256) {
        int r = idx / HW2;
        int c = idx - r * HW2;
        int gy = by0 + r - PAD; gy = min(max(gy, 0), HH - 1);
        int gx = bx0 + c - PAD; gx = min(max(gx, 0), WW - 1);
        size_t o = (size_t)gy * WW + gx;
        float a0 = albB[o] * kA, a1 = albB[plane + o] * kA, a2 = albB[2 * plane + o] * kA;
        float n0 = nrmB[o] * kN, n1 = nrmB[plane + o] * kN, n2 = nrmB[2 * plane + o] * kN;
        float d0 = depB[o] * kN;
        sG[r][c] = make_uint4(pk2(a0, a1), pk2(a2, d0), pk2(n0, n1), pk2(n2, 0.f));
        float i0 = inpB[o], i1 = inpB[plane + o], i2 = inpB[2 * plane + o];
        sI[r][c] = make_uint2(pk2(i0, i1), pk2(i2, 1.f));
    }
    __syncthreads();

    // ---- per-thread: 4 vertically adjacent pixels, tile rows 4*ly + 0..3 ----
    const int py0 = 4 * ly;

    uint4 gc0 = sG[py0 + 0 + PAD][lx + PAD];
    uint4 gc1 = sG[py0 + 1 + PAD][lx + PAD];
    uint4 gc2 = sG[py0 + 2 + PAD][lx + PAD];
    uint4 gc3 = sG[py0 + 3 + PAD][lx + PAD];
    Ctr c0 = { bch2(gc0.x), bch2(gc0.y), bch2(gc0.z), bch2(gc0.w) };
    Ctr c1 = { bch2(gc1.x), bch2(gc1.y), bch2(gc1.z), bch2(gc1.w) };
    Ctr c2 = { bch2(gc2.x), bch2(gc2.y), bch2(gc2.z), bch2(gc2.w) };
    Ctr c3 = { bch2(gc3.x), bch2(gc3.y), bch2(gc3.z), bch2(gc3.w) };

    float4 a0 = make_float4(0.f, 0.f, 0.f, 0.f);
    float4 a1 = make_float4(0.f, 0.f, 0.f, 0.f);
    float4 a2 = make_float4(0.f, 0.f, 0.f, 0.f);
    float4 a3 = make_float4(0.f, 0.f, 0.f, 0.f);

    // ramp-up rows t = 0,1,2 (pixel k active iff 0 <= t-k <= 10)
    do_row<0, 0>(&sG[py0 + 0][lx], &sI[py0 + 0][lx], c0, c1, c2, c3, a0, a1, a2, a3);
    do_row<0, 1>(&sG[py0 + 1][lx], &sI[py0 + 1][lx], c0, c1, c2, c3, a0, a1, a2, a3);
    do_row<0, 2>(&sG[py0 + 2][lx], &sI[py0 + 2][lx], c0, c1, c2, c3, a0, a1, a2, a3);
    // steady rows t = 3..10: all four pixels
#pragma unroll 1
    for (int t = 3; t <= 10; ++t)
        do_row<0, 3>(&sG[py0 + t][lx], &sI[py0 + t][lx], c0, c1, c2, c3, a0, a1, a2, a3);
    // ramp-down rows t = 11,12,13
    do_row<1, 3>(&sG[py0 + 11][lx], &sI[py0 + 11][lx], c0, c1, c2, c3, a0, a1, a2, a3);
    do_row<2, 3>(&sG[py0 + 12][lx], &sI[py0 + 12][lx], c0, c1, c2, c3, a0, a1, a2, a3);
    do_row<3, 3>(&sG[py0 + 13][lx], &sI[py0 + 13][lx], c0, c1, c2, c3, a0, a1, a2, a3);

    // ---- write out (guard H tail: grid y = ceil(720/32) = 23) ----
    const int ox = bx0 + lx;
    float* outB = out + (size_t)b * 3 * plane;
    {
        int oy = by0 + py0 + 0;
        if (oy < HH) {
            float inv = 1.0f / fmaxf(a0.w, 1e-10f);
            size_t o = (size_t)oy * WW + ox;
            outB[o] = a0.x * inv; outB[plane + o] = a0.y * inv; outB[2 * plane + o] = a0.z * inv;
        }
    }
    {
        int oy = by0 + py0 + 1;
        if (oy < HH) {
            float inv = 1.0f / fmaxf(a1.w, 1e-10f);
            size_t o = (size_t)oy * WW + ox;
            outB[o] = a1.x * inv; outB[plane + o] = a1.y * inv; outB[2 * plane + o] = a1.z * inv;
        }
    }
    {
        int oy = by0 + py0 + 2;
        if (oy < HH) {
            float inv = 1.0f / fmaxf(a2.w, 1e-10f);
            size_t o = (size_t)oy * WW + ox;
            outB[o] = a2.x * inv; outB[plane + o] = a2.y * inv; outB[2 * plane + o] = a2.z * inv;
        }
    }
    {
        int oy = by0 + py0 + 3;
        if (oy < HH) {
            float inv = 1.0f / fmaxf(a3.w, 1e-10f);
            size_t o = (size_t)oy * WW + ox;
            outB[o] = a3.x * inv; outB[plane + o] = a3.y * inv; outB[2 * plane + o] = a3.z * inv;
        }
    }
}

extern "C" void kernel_launch(void* const* d_in, const int* in_sizes, int n_in,
                              void* d_out, int out_size, void* d_ws, size_t ws_size,
                              hipStream_t stream) {
    const float* inp = (const float*)d_in[0];
    const float* alb = (const float*)d_in[1];
    const float* nrm = (const float*)d_in[2];
    const float* dep = (const float*)d_in[3];
    // d_in[4] = win_size (always 11, compiled in)
    float* out = (float*)d_out;

    dim3 grid(WW / TW, (HH + TH - 1) / TH, 4);   // 40 x 23 x 4
    dim3 block(256);
    xbilateral_kernel<<<grid, block, 0, stream>>>(inp, alb, nrm, dep, out);
}